// Round 5
// baseline (330.541 us; speedup 1.0000x reference)
//
#include <hip/hip_runtime.h>
#include <hip/hip_bf16.h>

#define BM 128
#define BN 128
// BK = 64, staged as two bank-safe BK=32 half-tiles (m97 layout per half)

typedef __bf16 bf16x8 __attribute__((ext_vector_type(8)));
typedef float f32x4 __attribute__((ext_vector_type(4)));
typedef unsigned short u16;

__device__ __forceinline__ u16 f2bf(float f) {
    __bf16 b = (__bf16)f;
    return __builtin_bit_cast(u16, b);
}
__device__ __forceinline__ float bf2f(u16 u) {
    __bf16 b = __builtin_bit_cast(__bf16, u);
    return (float)b;
}

__device__ __forceinline__ void gload_lds16(const void* g, void* l) {
    __builtin_amdgcn_global_load_lds(
        (const __attribute__((address_space(1))) void*)g,
        (__attribute__((address_space(3))) void*)l,
        16, 0, 0);
}

// ---------------------------------------------------------------------------
// Legacy 128x128 kernel — retained for G3 (MODE 2, triangular) and G4 (MODE 3,
// K-clipped at the 128-granular diagonal, which matches attnb's written tiles).
// ---------------------------------------------------------------------------
template <int MODE>
__global__ __launch_bounds__(256)
void gemm_bt(const u16* __restrict__ A, int lda, long long a_bs,
             const u16* __restrict__ Bt, int ldb, long long b_bs,
             int Kdim, int ldc, long long c_bs,
             const float* __restrict__ bias, float scale,
             const void* __restrict__ resid, long long r_bs,
             void* __restrict__ out, int causal)
{
    int bx = blockIdx.x, by = blockIdx.y, bz = blockIdx.z;
    if (causal == 3) {
        const int t = blockIdx.x;
        int byy = (int)((sqrtf(8.f * (float)t + 1.f) - 1.f) * 0.5f);
        while ((byy + 1) * (byy + 2) / 2 <= t) byy++;
        while (byy * (byy + 1) / 2 > t) byy--;
        by = byy; bx = t - byy * (byy + 1) / 2; bz = blockIdx.y;
    }
    if (causal == 2 && bz >= 2) by = (int)gridDim.y - 1 - by;  // pair long/short K rows per CU
    const int kend = (causal == 2) ? min(Kdim, (by + 1) * BM) : Kdim;

    A  += (long long)bz * a_bs;
    Bt += (long long)bz * b_bs;

    const int m0 = by * BM, n0 = bx * BN;
    const int tid = threadIdx.x;
    const int wave = tid >> 6, lane = tid & 63;
    const int wy = wave >> 1, wx = wave & 1;
    const int lr = lane >> 2, lc8 = (lane & 3) * 8;
    const int lane15 = lane & 15, kq = lane >> 4;

    __shared__ __align__(16) u16 As[2][BM * 32];
    __shared__ __align__(16) u16 Bs[2][BN * 32];

    f32x4 acc[4][4] = {};

    for (int k0 = 0; k0 < kend; k0 += 64) {
        __syncthreads();
        #pragma unroll
        for (int h = 0; h < 2; h++) {
            const int kh = k0 + h * 32 + lc8;
            #pragma unroll
            for (int it = 0; it < 2; it++) {
                const int row = wave * 16 + it * 64 + lr;
                gload_lds16(A  + (size_t)(m0 + row) * lda + kh,
                            &As[h][(wave * 16 + it * 64) * 32]);
                gload_lds16(Bt + (size_t)(n0 + row) * ldb + kh,
                            &Bs[h][(wave * 16 + it * 64) * 32]);
            }
        }
        __syncthreads();

        #pragma unroll
        for (int h = 0; h < 2; h++) {
            bf16x8 av[4], bv[4];
            #pragma unroll
            for (int i = 0; i < 4; i++)
                av[i] = *(const bf16x8*)&As[h][(wy * 64 + i * 16 + lane15) * 32 + kq * 8];
            #pragma unroll
            for (int j = 0; j < 4; j++)
                bv[j] = *(const bf16x8*)&Bs[h][(wx * 64 + j * 16 + lane15) * 32 + kq * 8];
            #pragma unroll
            for (int i = 0; i < 4; i++)
                #pragma unroll
                for (int j = 0; j < 4; j++)
                    acc[i][j] = __builtin_amdgcn_mfma_f32_16x16x32_bf16(av[i], bv[j], acc[i][j], 0, 0, 0);
        }
    }

    // Epilogue. C/D layout (m89-verified): col = lane&15, row = (lane>>4)*4 + reg.
    #pragma unroll
    for (int i = 0; i < 4; i++) {
        const int rl = m0 + wy * 64 + i * 16 + kq * 4;
        #pragma unroll
        for (int j = 0; j < 4; j++) {
            const int c = n0 + wx * 64 + j * 16 + lane15;
            #pragma unroll
            for (int rg = 0; rg < 4; rg++) {
                const int r = rl + rg;
                const size_t idx = (size_t)bz * c_bs + (size_t)r * ldc + c;
                const float v = acc[i][j][rg];
                if (MODE == 2) {
                    float p = __expf(v * scale);
                    if (c > r) p = 0.f;          // causal mask inside diagonal tile
                    ((u16*)out)[idx] = f2bf(p);
                } else if (MODE == 3) {
                    const u16* xr = (const u16*)resid;
                    const float linv = bias[(size_t)bz * 2048 + r];
                    const float h = bf2f(xr[(size_t)bz * r_bs + (size_t)r * ldc + c]) + v * linv;
                    ((u16*)out)[idx] = f2bf(h);
                }
            }
        }
    }
}

// ---------------------------------------------------------------------------
// 256x128 two-phase pipelined kernel (G12/G5/G6): 512 threads = 8 waves
// (4M x 2N), 64x64 per wave, BK=64 split into two 32-col half-K phases.
// Ring of THREE SEPARATE __shared__ objects per operand (not a [3] array):
// the memory legalizer's LDS-DMA alias tracking is per-object, so ds_reads of
// buffer i provably don't alias outstanding global_load_lds DMAs to buffers
// j != i, and no conservative vmcnt drain is inserted before each phase's
// reads (round-2 diagnosis of the ~2000 cyc/phase stall). K-loop is fully
// unrolled (NT=16 constant) so every ring select constant-folds to a direct
// object reference.
//
// Per phase: {8x ds_read_b128 (plain C++) || stage one half-group (3
// gload_lds, tile t+2) -> counted vmcnt -> s_barrier -> lgkmcnt(0) ->
// setprio(1) -> 16 MFMA -> setprio(0) -> s_barrier}.
//
// vmcnt ledger (per-wave VMEM instr, groups of 3, in-order retirement):
// group p+4 issued at phase p, consumed at phase p+4. Phase p's vmcnt(9)
// guarantees groups <= p+1 landed; its barrier publishes them for phase
// p+1's reads. Tail: 6 -> 3 -> 0 -> 0.
//
// Bank swizzle (round-1/2 verified, 0 conflicts): within each 1024B staging
// block, pi(slot) = slot ^ ((slot>>3)&3) via pre-swizzled GLOBAL source
// (gload_lds dest stays linear, rule #21) + swizzled ds_read offset.
//
// MODE 4: bf16 out = relu(acc + bias)                         (FFN1)
// MODE 5: fp32 out = acc + bias + bf16(resid)                 (FFN2 + residual)
// MODE 6: merged QKV: n0<512 -> bf16 QK + bias; else Vt transposed + bias
// ---------------------------------------------------------------------------
template <int MODE>
__global__ __launch_bounds__(512, 2)
void gemm_bt2(const u16* __restrict__ A, int lda,
              const u16* __restrict__ Bt, int ldb,
              int ldc,
              const float* __restrict__ bias,
              const void* __restrict__ resid,
              void* __restrict__ out)
{
    constexpr int NT = 16;   // K = NT*64 = 1024 (fixed for this problem)
    const int m0 = blockIdx.y * 256, n0 = blockIdx.x * 128;
    const int tid = threadIdx.x;
    const int wave = tid >> 6, lane = tid & 63;
    const int wr = wave >> 1, wc = wave & 1;      // 4 x 2 wave grid
    const int lane15 = lane & 15, kq = lane >> 4;
    const int lr = lane >> 2;
    const int swzc8 = ((lane & 3) ^ ((lane >> 3) & 3)) * 8;               // staging source k-slot
    const int lslot = lane15 * 32 + ((kq ^ ((lane15 >> 1) & 3)) * 8);     // swizzled read offset

    __shared__ __align__(16) u16 As0[2][256 * 32];   // 32 KiB each
    __shared__ __align__(16) u16 As1[2][256 * 32];
    __shared__ __align__(16) u16 As2[2][256 * 32];
    __shared__ __align__(16) u16 Bs0[2][128 * 32];   // 16 KiB each
    __shared__ __align__(16) u16 Bs1[2][128 * 32];
    __shared__ __align__(16) u16 Bs2[2][128 * 32];   // total 144 KiB

    f32x4 acc[4][4] = {};

    // One half-group: 2 A loads + 1 B load for half-K h of tile tt (3 VMEM instr).
    auto stage_h = [&](u16 (*Ad)[256 * 32], u16 (*Bd)[128 * 32], int tt, int h) {
        const int kh = (tt << 6) + h * 32 + swzc8;
        #pragma unroll
        for (int it = 0; it < 2; it++) {
            const int row = wave * 16 + it * 128 + lr;
            gload_lds16(A + (size_t)(m0 + row) * lda + kh,
                        &Ad[h][(wave * 16 + it * 128) * 32]);
        }
        gload_lds16(Bt + (size_t)(n0 + wave * 16 + lr) * ldb + kh,
                    &Bd[h][(wave * 16) * 32]);
    };

#define PHASE(PA, PB, H, STAGE_STMT, VM)                                       \
    {                                                                          \
        bf16x8 av[4], bv[4];                                                   \
        _Pragma("unroll")                                                      \
        for (int i = 0; i < 4; i++)                                            \
            av[i] = *(const bf16x8*)&(PA)[H][(wr * 4 + i) * 512 + lslot];      \
        _Pragma("unroll")                                                      \
        for (int j = 0; j < 4; j++)                                            \
            bv[j] = *(const bf16x8*)&(PB)[H][(wc * 4 + j) * 512 + lslot];      \
        STAGE_STMT;                                                            \
        asm volatile("s_waitcnt vmcnt(" #VM ")" ::: "memory");                 \
        __builtin_amdgcn_s_barrier();                                          \
        asm volatile("s_waitcnt lgkmcnt(0)" ::: "memory");                     \
        __builtin_amdgcn_s_setprio(1);                                         \
        _Pragma("unroll")                                                      \
        for (int i = 0; i < 4; i++)                                            \
            _Pragma("unroll")                                                  \
            for (int j = 0; j < 4; j++)                                        \
                acc[i][j] = __builtin_amdgcn_mfma_f32_16x16x32_bf16(           \
                    av[i], bv[j], acc[i][j], 0, 0, 0);                         \
        __builtin_amdgcn_s_setprio(0);                                         \
        __builtin_amdgcn_s_barrier();                                          \
    }

    // Prologue: groups 0..3 (tiles 0,1), wait oldest 3 (group 0), barrier.
    stage_h(As0, Bs0, 0, 0); stage_h(As0, Bs0, 0, 1);
    stage_h(As1, Bs1, 1, 0); stage_h(As1, Bs1, 1, 1);
    asm volatile("s_waitcnt vmcnt(9)" ::: "memory");
    __builtin_amdgcn_s_barrier();

    // Steady state, fully unrolled: ring index t%3 / (t+2)%3 constant-folds.
    #pragma unroll
    for (int t = 0; t < NT - 2; t++) {
        u16 (*pAc)[256 * 32] = (t % 3 == 0) ? As0 : (t % 3 == 1) ? As1 : As2;
        u16 (*pBc)[128 * 32] = (t % 3 == 0) ? Bs0 : (t % 3 == 1) ? Bs1 : Bs2;
        const int tn = (t + 2) % 3;
        u16 (*pAn)[256 * 32] = (tn == 0) ? As0 : (tn == 1) ? As1 : As2;
        u16 (*pBn)[128 * 32] = (tn == 0) ? Bs0 : (tn == 1) ? Bs1 : Bs2;
        PHASE(pAc, pBc, 0, stage_h(pAn, pBn, t + 2, 0), 9)
        PHASE(pAc, pBc, 1, stage_h(pAn, pBn, t + 2, 1), 9)
    }
    // t = NT-2 = 14 -> ring 2; no more staging; ledger drains 6 -> 3.
    PHASE(As2, Bs2, 0, (void)0, 6)
    PHASE(As2, Bs2, 1, (void)0, 3)
    // t = NT-1 = 15 -> ring 0; final tile, drain to 0.
    PHASE(As0, Bs0, 0, (void)0, 0)
    PHASE(As0, Bs0, 1, (void)0, 0)
#undef PHASE

    // Epilogue. C/D layout: col = lane&15, row = (lane>>4)*4 + reg.
    if (MODE == 6 && n0 >= 512) {
        u16* o = (u16*)resid;  // Vt[b][c-512][s], second output pointer
        #pragma unroll
        for (int i = 0; i < 4; i++) {
            const int r = m0 + wr * 64 + i * 16 + kq * 4;
            const size_t base = (size_t)(r >> 11) * 1024 * 2048 + (r & 2047);
            #pragma unroll
            for (int j = 0; j < 4; j++) {
                const int c = n0 + wc * 64 + j * 16 + lane15;
                const float bj = bias[c];
                ushort4 pk;
                pk.x = f2bf(acc[i][j][0] + bj);
                pk.y = f2bf(acc[i][j][1] + bj);
                pk.z = f2bf(acc[i][j][2] + bj);
                pk.w = f2bf(acc[i][j][3] + bj);
                *(ushort4*)&o[base + (size_t)(c - 512) * 2048] = pk;
            }
        }
    } else {
        #pragma unroll
        for (int i = 0; i < 4; i++) {
            const int rl = m0 + wr * 64 + i * 16 + kq * 4;
            #pragma unroll
            for (int j = 0; j < 4; j++) {
                const int c = n0 + wc * 64 + j * 16 + lane15;
                const float bj = bias[c];
                #pragma unroll
                for (int rg = 0; rg < 4; rg++) {
                    const int r = rl + rg;
                    const size_t idx = (size_t)r * ldc + c;
                    const float v = acc[i][j][rg];
                    if (MODE == 4) {
                        ((u16*)out)[idx] = f2bf(fmaxf(v + bj, 0.f));
                    } else if (MODE == 5) {
                        const u16* hb = (const u16*)resid;
                        ((float*)out)[idx] = v + bj + bf2f(hb[idx]);
                    } else if (MODE == 6) {
                        ((u16*)out)[idx] = f2bf(v + bj);
                    }
                }
            }
        }
    }
}

// x fp32 -> bf16, vectorized (float4 in, ushort4 out).
__global__ __launch_bounds__(256)
void prep_x(const float* __restrict__ x, u16* __restrict__ xb)
{
    const int N4 = 8388608 / 4;
    for (int i = blockIdx.x * blockDim.x + threadIdx.x; i < N4; i += gridDim.x * blockDim.x) {
        const float4 v = ((const float4*)x)[i];
        ushort4 o;
        o.x = f2bf(v.x); o.y = f2bf(v.y); o.z = f2bf(v.z); o.w = f2bf(v.w);
        ((ushort4*)xb)[i] = o;
    }
}

// Coalesced LDS-tiled transpose+convert of all weights, plus bias concat.
// Blocks 0..127: Wq/Wk -> WqkT[512][1024]; 128..895: Wv/W1/W2 -> [1024][1024]T; 896: biases.
__global__ __launch_bounds__(256)
void prep_w(const float* __restrict__ Wq, const float* __restrict__ bq,
            const float* __restrict__ Wk, const float* __restrict__ bk,
            const float* __restrict__ Wv, const float* __restrict__ bv,
            const float* __restrict__ b1, const float* __restrict__ b2,
            const float* __restrict__ W1, const float* __restrict__ W2,
            u16* __restrict__ WqkT, u16* __restrict__ WvT,
            u16* __restrict__ W1T, u16* __restrict__ W2T, float* __restrict__ biasv)
{
    const int bid = blockIdx.x, tid = threadIdx.x;
    if (bid == 896) {
        for (int t = tid; t < 3584; t += 256) {
            if (t < 512)       biasv[t] = (t < 256) ? bq[t] : bk[t - 256];
            else if (t < 1536) biasv[t] = bv[t - 512];
            else if (t < 2560) biasv[t] = b1[t - 1536];
            else               biasv[t] = b2[t - 2560];
        }
        return;
    }
    const float* src; u16* dst; int ld_src, kt, nt, nbase;
    if (bid < 128) {
        const int job = bid >> 6, t = bid & 63;
        src = job ? Wk : Wq; ld_src = 256;
        kt = t >> 2; nt = t & 3; nbase = job * 256 + nt * 64;
        dst = WqkT;
    } else {
        const int j = bid - 128, w = j >> 8, t = j & 255;
        src = (w == 0) ? Wv : (w == 1) ? W1 : W2; ld_src = 1024;
        kt = t >> 4; nt = t & 15; nbase = nt * 64;
        dst = (w == 0) ? WvT : (w == 1) ? W1T : W2T;
    }
    const int k0 = kt * 64;
    const int n0s = (ld_src == 256) ? (nbase & 255) : nbase;

    __shared__ float tile[64][65];
    // read 64 rows (k) x 64 cols (n), coalesced float4
    const int ri = tid >> 4, j4 = (tid & 15) * 4;
    #pragma unroll
    for (int rr = 0; rr < 4; rr++) {
        const int i = ri + rr * 16;
        const float4 v = *(const float4*)&src[(size_t)(k0 + i) * ld_src + n0s + j4];
        tile[j4 + 0][i] = v.x;
        tile[j4 + 1][i] = v.y;
        tile[j4 + 2][i] = v.z;
        tile[j4 + 3][i] = v.w;
    }
    __syncthreads();
    // write 64 n-rows x 64 k, coalesced u16
    const int n = tid >> 2, ks = (tid & 3) * 16;
    ushort4 o[4];
    #pragma unroll
    for (int c = 0; c < 4; c++) {
        o[c].x = f2bf(tile[n][ks + c * 4 + 0]);
        o[c].y = f2bf(tile[n][ks + c * 4 + 1]);
        o[c].z = f2bf(tile[n][ks + c * 4 + 2]);
        o[c].w = f2bf(tile[n][ks + c * 4 + 3]);
    }
    u16* drow = &dst[(size_t)(nbase + n) * 1024 + k0 + ks];
    #pragma unroll
    for (int c = 0; c < 4; c++) *(ushort4*)&drow[c * 4] = o[c];
}

__device__ __forceinline__ float wave_sum(float v) {
    #pragma unroll
    for (int off = 32; off > 0; off >>= 1) v += __shfl_xor(v, off, 64);
    return v;
}

// One block per (b,q) row. Fully vectorized: P has exact zeros for c in (r, kpad)
// (G3 masks the diagonal tile), so no per-element validity masking is needed.
__global__ __launch_bounds__(256)
void norm_kernel(const u16* __restrict__ attnb, float* __restrict__ attn,
                 float* __restrict__ linv)
{
    const int S = 2048;
    const int row = blockIdx.x;
    const int q = row & (S - 1);
    const int kpad = (q + 128) & ~127;   // ceil((q+1)/128)*128
    const u16* brow = attnb + (size_t)row * S;
    float* srow = attn + (size_t)row * S;
    __shared__ float red[4];
    const int tid = threadIdx.x, wv = tid >> 6, ln = tid & 63;
    const int k = tid * 8;

    float vals[8];
    float lsum = 0.f;
    if (k < kpad) {
        const ushort4 a = *(const ushort4*)&brow[k];
        const ushort4 b = *(const ushort4*)&brow[k + 4];
        vals[0] = bf2f(a.x); vals[1] = bf2f(a.y); vals[2] = bf2f(a.z); vals[3] = bf2f(a.w);
        vals[4] = bf2f(b.x); vals[5] = bf2f(b.y); vals[6] = bf2f(b.z); vals[7] = bf2f(b.w);
        #pragma unroll
        for (int c = 0; c < 8; c++) lsum += vals[c];
    }
    lsum = wave_sum(lsum);
    if (ln == 0) red[wv] = lsum;
    __syncthreads();
    const float rinv = 1.f / (red[0] + red[1] + red[2] + red[3]);

    float4 o0 = {0.f, 0.f, 0.f, 0.f}, o1 = {0.f, 0.f, 0.f, 0.f};
    if (k < kpad) {
        o0 = make_float4(vals[0] * rinv, vals[1] * rinv, vals[2] * rinv, vals[3] * rinv);
        o1 = make_float4(vals[4] * rinv, vals[5] * rinv, vals[6] * rinv, vals[7] * rinv);
    }
    *(float4*)&srow[k] = o0;
    *(float4*)&srow[k + 4] = o1;
    if (tid == 0) linv[row] = rinv;
}

extern "C" void kernel_launch(void* const* d_in, const int* in_sizes, int n_in,
                              void* d_out, int out_size, void* d_ws, size_t ws_size,
                              hipStream_t stream)
{
    const float* x  = (const float*)d_in[0];
    const float* Wq = (const float*)d_in[1];
    const float* bq = (const float*)d_in[2];
    const float* Wk = (const float*)d_in[3];
    const float* bk = (const float*)d_in[4];
    const float* Wv = (const float*)d_in[5];
    const float* bv = (const float*)d_in[6];
    const float* W1 = (const float*)d_in[7];
    const float* b1 = (const float*)d_in[8];
    const float* W2 = (const float*)d_in[9];
    const float* b2 = (const float*)d_in[10];

    const int B = 4, S = 2048, D = 1024, BS = B * S;

    char* ws = (char*)d_ws;
    u16*   xb    = (u16*)(ws + 0);            // 16 MB, aliased by h_b after G4
    u16*   WqkT  = (u16*)(ws + 16777216);     // 1 MB  (contiguous with WvT -> [1536][1024])
    u16*   WvT   = (u16*)(ws + 17825792);     // 2 MB
    u16*   W1T   = (u16*)(ws + 19922944);     // 2 MB
    u16*   W2T   = (u16*)(ws + 22020096);     // 2 MB
    float* biasv = (float*)(ws + 24117248);   // 16 KB: [bq|bk][bv][b1][b2]
    u16*   QK    = (u16*)(ws + 24133632);     // 8 MB: [8192][512] = [Q|K]
    u16*   Vt    = (u16*)(ws + 32522240);     // 16 MB: [4][1024][2048]
    u16*   attnb = (u16*)(ws + 49299456);     // 32 MB raw exp-P, aliased by ff1 after G4
    float* linv  = (float*)(ws + 83886080);   // 32 KB
    u16*   hb    = xb;
    u16*   ff1   = attnb;

    float* out0 = (float*)d_out;
    float* attn = out0 + (size_t)BS * D;

    const dim3 blk(256);

    prep_x<<<dim3(1024), blk, 0, stream>>>(x, xb);
    prep_w<<<dim3(897), blk, 0, stream>>>(Wq, bq, Wk, bk, Wv, bv, b1, b2, W1, W2,
                                          WqkT, WvT, W1T, W2T, biasv);

    // G12 merged: [Q|K|V] = x @ [Wq|Wk|Wv] + bias   (M=8192, N=1536, K=1024, 384 blocks)
    gemm_bt2<6><<<dim3(12, 32), dim3(512), 0, stream>>>(
        xb, 1024, WqkT, 1024, 512, biasv, Vt, QK);

    // G3: P = exp(Q @ K^T / 16), causal-masked, bf16, triangular grid (544 blocks)
    gemm_bt<2><<<dim3(136, 4, 1), blk, 0, stream>>>(
        QK, 512, (long long)S * 512, QK + 256, 512, (long long)S * 512,
        256, S, (long long)S * S, nullptr, 0.0625f, nullptr, 0, attnb, 3);

    // normalize: attn_fp32 = P / l (d_out), linv = 1/l
    norm_kernel<<<dim3(BS), blk, 0, stream>>>(attnb, attn, linv);

    // G4: h = bf16(x) + (P @ V) * linv  (512 blocks, K clipped at diagonal, by-pairing)
    gemm_bt<3><<<dim3(8, 16, 4), blk, 0, stream>>>(
        attnb, S, (long long)S * S, Vt, S, (long long)D * S,
        S, D, (long long)S * D, linv, 1.f, xb, (long long)S * D, hb, 2);

    // G5: ff1 = relu(h @ W1 + b1)  (M=8192, N=1024, K=1024, 256 blocks)
    gemm_bt2<4><<<dim3(8, 32), dim3(512), 0, stream>>>(
        hb, 1024, W1T, 1024, 1024, biasv + 1536, nullptr, ff1);

    // G6: out0 = h + ff1 @ W2 + b2  (M=8192, N=1024, K=1024, 256 blocks)
    gemm_bt2<5><<<dim3(8, 32), dim3(512), 0, stream>>>(
        ff1, 1024, W2T, 1024, 1024, biasv + 2560, hb, out0);
}

// Round 6
// 303.599 us; speedup vs baseline: 1.0887x; 1.0887x over previous
//
#include <hip/hip_runtime.h>
#include <hip/hip_bf16.h>

#define BM 128
#define BN 128
// BK = 64, staged as two bank-safe BK=32 half-tiles (m97 layout per half)

typedef __bf16 bf16x8 __attribute__((ext_vector_type(8)));
typedef float f32x4 __attribute__((ext_vector_type(4)));
typedef unsigned short u16;

__device__ __forceinline__ u16 f2bf(float f) {
    __bf16 b = (__bf16)f;
    return __builtin_bit_cast(u16, b);
}
__device__ __forceinline__ float bf2f(u16 u) {
    __bf16 b = __builtin_bit_cast(__bf16, u);
    return (float)b;
}

__device__ __forceinline__ void gload_lds16(const void* g, void* l) {
    __builtin_amdgcn_global_load_lds(
        (const __attribute__((address_space(1))) void*)g,
        (__attribute__((address_space(3))) void*)l,
        16, 0, 0);
}

// Inline-asm LDS read: invisible to the memory legalizer, so it cannot insert
// conservative vmcnt drains against outstanding global_load_lds DMA (the
// round-2 diagnosis of the per-phase stall). Completion is enforced manually
// via counted lgkmcnt + sched_barrier(0) before the consuming MFMAs (rule #18).
__device__ __forceinline__ bf16x8 lds_read_b128(const u16* p) {
    bf16x8 r;
    const __attribute__((address_space(3))) u16* lp =
        (const __attribute__((address_space(3))) u16*)p;
    asm volatile("ds_read_b128 %0, %1" : "=v"(r) : "v"(lp));
    return r;
}

// ---------------------------------------------------------------------------
// Legacy 128x128 kernel — retained for G3 (MODE 2, triangular) and G4 (MODE 3,
// K-clipped at the 128-granular diagonal, which matches attnb's written tiles).
// ---------------------------------------------------------------------------
template <int MODE>
__global__ __launch_bounds__(256)
void gemm_bt(const u16* __restrict__ A, int lda, long long a_bs,
             const u16* __restrict__ Bt, int ldb, long long b_bs,
             int Kdim, int ldc, long long c_bs,
             const float* __restrict__ bias, float scale,
             const void* __restrict__ resid, long long r_bs,
             void* __restrict__ out, int causal)
{
    int bx = blockIdx.x, by = blockIdx.y, bz = blockIdx.z;
    if (causal == 3) {
        const int t = blockIdx.x;
        int byy = (int)((sqrtf(8.f * (float)t + 1.f) - 1.f) * 0.5f);
        while ((byy + 1) * (byy + 2) / 2 <= t) byy++;
        while (byy * (byy + 1) / 2 > t) byy--;
        by = byy; bx = t - byy * (byy + 1) / 2; bz = blockIdx.y;
    }
    if (causal == 2 && bz >= 2) by = (int)gridDim.y - 1 - by;  // pair long/short K rows per CU
    const int kend = (causal == 2) ? min(Kdim, (by + 1) * BM) : Kdim;

    A  += (long long)bz * a_bs;
    Bt += (long long)bz * b_bs;

    const int m0 = by * BM, n0 = bx * BN;
    const int tid = threadIdx.x;
    const int wave = tid >> 6, lane = tid & 63;
    const int wy = wave >> 1, wx = wave & 1;
    const int lr = lane >> 2, lc8 = (lane & 3) * 8;
    const int lane15 = lane & 15, kq = lane >> 4;

    __shared__ __align__(16) u16 As[2][BM * 32];
    __shared__ __align__(16) u16 Bs[2][BN * 32];

    f32x4 acc[4][4] = {};

    for (int k0 = 0; k0 < kend; k0 += 64) {
        __syncthreads();
        #pragma unroll
        for (int h = 0; h < 2; h++) {
            const int kh = k0 + h * 32 + lc8;
            #pragma unroll
            for (int it = 0; it < 2; it++) {
                const int row = wave * 16 + it * 64 + lr;
                gload_lds16(A  + (size_t)(m0 + row) * lda + kh,
                            &As[h][(wave * 16 + it * 64) * 32]);
                gload_lds16(Bt + (size_t)(n0 + row) * ldb + kh,
                            &Bs[h][(wave * 16 + it * 64) * 32]);
            }
        }
        __syncthreads();

        #pragma unroll
        for (int h = 0; h < 2; h++) {
            bf16x8 av[4], bv[4];
            #pragma unroll
            for (int i = 0; i < 4; i++)
                av[i] = *(const bf16x8*)&As[h][(wy * 64 + i * 16 + lane15) * 32 + kq * 8];
            #pragma unroll
            for (int j = 0; j < 4; j++)
                bv[j] = *(const bf16x8*)&Bs[h][(wx * 64 + j * 16 + lane15) * 32 + kq * 8];
            #pragma unroll
            for (int i = 0; i < 4; i++)
                #pragma unroll
                for (int j = 0; j < 4; j++)
                    acc[i][j] = __builtin_amdgcn_mfma_f32_16x16x32_bf16(av[i], bv[j], acc[i][j], 0, 0, 0);
        }
    }

    // Epilogue. C/D layout (m89-verified): col = lane&15, row = (lane>>4)*4 + reg.
    #pragma unroll
    for (int i = 0; i < 4; i++) {
        const int rl = m0 + wy * 64 + i * 16 + kq * 4;
        #pragma unroll
        for (int j = 0; j < 4; j++) {
            const int c = n0 + wx * 64 + j * 16 + lane15;
            #pragma unroll
            for (int rg = 0; rg < 4; rg++) {
                const int r = rl + rg;
                const size_t idx = (size_t)bz * c_bs + (size_t)r * ldc + c;
                const float v = acc[i][j][rg];
                if (MODE == 2) {
                    float p = __expf(v * scale);
                    if (c > r) p = 0.f;          // causal mask inside diagonal tile
                    ((u16*)out)[idx] = f2bf(p);
                } else if (MODE == 3) {
                    const u16* xr = (const u16*)resid;
                    const float linv = bias[(size_t)bz * 2048 + r];
                    const float h = bf2f(xr[(size_t)bz * r_bs + (size_t)r * ldc + c]) + v * linv;
                    ((u16*)out)[idx] = f2bf(h);
                }
            }
        }
    }
}

// ---------------------------------------------------------------------------
// 256x128 free-running pipelined kernel (G12/G5/G6): 512 threads = 8 waves
// (4M x 2N), 64x64 per wave, BK=64. 3-deep LDS ring of separate objects
// (144 KiB). ONE barrier per K-tile:
//   { vmcnt(6) -> s_barrier -> stage t+2 (6 gload_lds) ->
//     16 asm ds_read_b128 (h0:8, h1:8) ->
//     lgkmcnt(8) + sched_barrier(0) -> setprio(1) 16 MFMA (h0) setprio(0) ->
//     lgkmcnt(0) + sched_barrier(0) -> setprio(1) 16 MFMA (h1) setprio(0) }
// Waves free-run within the tile (no intra-tile barriers) -> cross-wave
// MFMA/VMEM overlap at 1 block/CU. asm ds_read keeps the memory legalizer
// from inserting conservative vmcnt drains; the ONLY waits are the counted
// ones above (never vmcnt(0) until the tail).
//
// vmcnt ledger (per-wave, 6 loads/tile, in-order retirement): tile t+2 staged
// during tile t; at top of tile t outstanding <= 12 (t+1's 6 + t+2's 6... i.e.
// t's were retired by the previous vmcnt) -> vmcnt(6) retires tile t's own 6.
// Safety: each wave waits on ITS OWN loads, then the s_barrier publishes all
// waves' rows before any read. Buffer overwrite: stage at tile t writes ring
// (t+2)%3 = (t-1)%3, whose readers all passed the top-of-t barrier (their
// ds_reads drained before their MFMAs, which precede the barrier).
//
// Bank swizzle (round-1/2/5 verified, 0 conflicts): within each 1024B staging
// block, pi(slot) = slot ^ ((slot>>3)&3) via pre-swizzled GLOBAL source
// (gload_lds dest stays linear, rule #21) + swizzled ds_read offset.
//
// T1 XCD-aware remap (bijective; nwg % 8 == 0 at all three call sites).
//
// MODE 4: bf16 out = relu(acc + bias)                         (FFN1)
// MODE 5: fp32 out = acc + bias + bf16(resid)                 (FFN2 + residual)
// MODE 6: merged QKV: n0<512 -> bf16 QK + bias; else Vt transposed + bias
// ---------------------------------------------------------------------------
template <int MODE>
__global__ __launch_bounds__(512, 2)
void gemm_bt2(const u16* __restrict__ A, int lda,
              const u16* __restrict__ Bt, int ldb,
              int ldc,
              const float* __restrict__ bias,
              const void* __restrict__ resid,
              void* __restrict__ out)
{
    constexpr int NT = 16;   // K = NT*64 = 1024 (fixed for this problem)
    // T1: blocks with lin % 8 == x all dispatch to XCD x (round-robin), so give
    // each XCD a contiguous chunk of the M-major work -> A-panels live in one L2.
    const int gx = gridDim.x;
    const int nwg = gx * (int)gridDim.y;
    int lin = blockIdx.y * gx + blockIdx.x;
    lin = (lin & 7) * (nwg >> 3) + (lin >> 3);
    const int m0 = (lin / gx) * 256, n0 = (lin % gx) * 128;

    const int tid = threadIdx.x;
    const int wave = tid >> 6, lane = tid & 63;
    const int wr = wave >> 1, wc = wave & 1;      // 4 x 2 wave grid
    const int lane15 = lane & 15, kq = lane >> 4;
    const int lr = lane >> 2;
    const int swzc8 = ((lane & 3) ^ ((lane >> 3) & 3)) * 8;               // staging source k-slot
    const int lslot = lane15 * 32 + ((kq ^ ((lane15 >> 1) & 3)) * 8);     // swizzled read offset

    __shared__ __align__(16) u16 As0[2][256 * 32];   // 32 KiB each
    __shared__ __align__(16) u16 As1[2][256 * 32];
    __shared__ __align__(16) u16 As2[2][256 * 32];
    __shared__ __align__(16) u16 Bs0[2][128 * 32];   // 16 KiB each
    __shared__ __align__(16) u16 Bs1[2][128 * 32];
    __shared__ __align__(16) u16 Bs2[2][128 * 32];   // total 144 KiB

    f32x4 acc[4][4] = {};

    // Full tile stage: 4 A loads + 2 B loads per thread (6 VMEM instr).
    auto stage = [&](u16 (*Ad)[256 * 32], u16 (*Bd)[128 * 32], int tt) {
        #pragma unroll
        for (int h = 0; h < 2; h++) {
            const int kh = (tt << 6) + h * 32 + swzc8;
            #pragma unroll
            for (int it = 0; it < 2; it++) {
                const int row = wave * 16 + it * 128 + lr;
                gload_lds16(A + (size_t)(m0 + row) * lda + kh,
                            &Ad[h][(wave * 16 + it * 128) * 32]);
            }
            gload_lds16(Bt + (size_t)(n0 + wave * 16 + lr) * ldb + kh,
                        &Bd[h][(wave * 16) * 32]);
        }
    };

    stage(As0, Bs0, 0);
    stage(As1, Bs1, 1);      // 12 loads outstanding

    #pragma unroll
    for (int t = 0; t < NT; t++) {
        u16 (*pAc)[256 * 32] = (t % 3 == 0) ? As0 : (t % 3 == 1) ? As1 : As2;
        u16 (*pBc)[128 * 32] = (t % 3 == 0) ? Bs0 : (t % 3 == 1) ? Bs1 : Bs2;
        if (t < NT - 1) asm volatile("s_waitcnt vmcnt(6)" ::: "memory");
        else            asm volatile("s_waitcnt vmcnt(0)" ::: "memory");
        __builtin_amdgcn_s_barrier();
        if (t + 2 < NT) {
            const int tn = (t + 2) % 3;
            u16 (*pAn)[256 * 32] = (tn == 0) ? As0 : (tn == 1) ? As1 : As2;
            u16 (*pBn)[128 * 32] = (tn == 0) ? Bs0 : (tn == 1) ? Bs1 : Bs2;
            stage(pAn, pBn, t + 2);
        }

        // Issue all 16 ds_reads (h0 first, then h1), then counted waits.
        bf16x8 av0[4], bv0[4], av1[4], bv1[4];
        #pragma unroll
        for (int i = 0; i < 4; i++)
            av0[i] = lds_read_b128(&pAc[0][(wr * 4 + i) * 512 + lslot]);
        #pragma unroll
        for (int j = 0; j < 4; j++)
            bv0[j] = lds_read_b128(&pBc[0][(wc * 4 + j) * 512 + lslot]);
        #pragma unroll
        for (int i = 0; i < 4; i++)
            av1[i] = lds_read_b128(&pAc[1][(wr * 4 + i) * 512 + lslot]);
        #pragma unroll
        for (int j = 0; j < 4; j++)
            bv1[j] = lds_read_b128(&pBc[1][(wc * 4 + j) * 512 + lslot]);

        asm volatile("s_waitcnt lgkmcnt(8)" ::: "memory");
        __builtin_amdgcn_sched_barrier(0);
        __builtin_amdgcn_s_setprio(1);
        #pragma unroll
        for (int i = 0; i < 4; i++)
            #pragma unroll
            for (int j = 0; j < 4; j++)
                acc[i][j] = __builtin_amdgcn_mfma_f32_16x16x32_bf16(av0[i], bv0[j], acc[i][j], 0, 0, 0);
        __builtin_amdgcn_s_setprio(0);

        asm volatile("s_waitcnt lgkmcnt(0)" ::: "memory");
        __builtin_amdgcn_sched_barrier(0);
        __builtin_amdgcn_s_setprio(1);
        #pragma unroll
        for (int i = 0; i < 4; i++)
            #pragma unroll
            for (int j = 0; j < 4; j++)
                acc[i][j] = __builtin_amdgcn_mfma_f32_16x16x32_bf16(av1[i], bv1[j], acc[i][j], 0, 0, 0);
        __builtin_amdgcn_s_setprio(0);
    }

    // Epilogue. C/D layout: col = lane&15, row = (lane>>4)*4 + reg.
    if (MODE == 6 && n0 >= 512) {
        u16* o = (u16*)resid;  // Vt[b][c-512][s], second output pointer
        #pragma unroll
        for (int i = 0; i < 4; i++) {
            const int r = m0 + wr * 64 + i * 16 + kq * 4;
            const size_t base = (size_t)(r >> 11) * 1024 * 2048 + (r & 2047);
            #pragma unroll
            for (int j = 0; j < 4; j++) {
                const int c = n0 + wc * 64 + j * 16 + lane15;
                const float bj = bias[c];
                ushort4 pk;
                pk.x = f2bf(acc[i][j][0] + bj);
                pk.y = f2bf(acc[i][j][1] + bj);
                pk.z = f2bf(acc[i][j][2] + bj);
                pk.w = f2bf(acc[i][j][3] + bj);
                *(ushort4*)&o[base + (size_t)(c - 512) * 2048] = pk;
            }
        }
    } else {
        #pragma unroll
        for (int i = 0; i < 4; i++) {
            const int rl = m0 + wr * 64 + i * 16 + kq * 4;
            #pragma unroll
            for (int j = 0; j < 4; j++) {
                const int c = n0 + wc * 64 + j * 16 + lane15;
                const float bj = bias[c];
                #pragma unroll
                for (int rg = 0; rg < 4; rg++) {
                    const int r = rl + rg;
                    const size_t idx = (size_t)r * ldc + c;
                    const float v = acc[i][j][rg];
                    if (MODE == 4) {
                        ((u16*)out)[idx] = f2bf(fmaxf(v + bj, 0.f));
                    } else if (MODE == 5) {
                        const u16* hb = (const u16*)resid;
                        ((float*)out)[idx] = v + bj + bf2f(hb[idx]);
                    } else if (MODE == 6) {
                        ((u16*)out)[idx] = f2bf(v + bj);
                    }
                }
            }
        }
    }
}

// x fp32 -> bf16, vectorized (float4 in, ushort4 out).
__global__ __launch_bounds__(256)
void prep_x(const float* __restrict__ x, u16* __restrict__ xb)
{
    const int N4 = 8388608 / 4;
    for (int i = blockIdx.x * blockDim.x + threadIdx.x; i < N4; i += gridDim.x * blockDim.x) {
        const float4 v = ((const float4*)x)[i];
        ushort4 o;
        o.x = f2bf(v.x); o.y = f2bf(v.y); o.z = f2bf(v.z); o.w = f2bf(v.w);
        ((ushort4*)xb)[i] = o;
    }
}

// Coalesced LDS-tiled transpose+convert of all weights, plus bias concat.
// Blocks 0..127: Wq/Wk -> WqkT[512][1024]; 128..895: Wv/W1/W2 -> [1024][1024]T; 896: biases.
__global__ __launch_bounds__(256)
void prep_w(const float* __restrict__ Wq, const float* __restrict__ bq,
            const float* __restrict__ Wk, const float* __restrict__ bk,
            const float* __restrict__ Wv, const float* __restrict__ bv,
            const float* __restrict__ b1, const float* __restrict__ b2,
            const float* __restrict__ W1, const float* __restrict__ W2,
            u16* __restrict__ WqkT, u16* __restrict__ WvT,
            u16* __restrict__ W1T, u16* __restrict__ W2T, float* __restrict__ biasv)
{
    const int bid = blockIdx.x, tid = threadIdx.x;
    if (bid == 896) {
        for (int t = tid; t < 3584; t += 256) {
            if (t < 512)       biasv[t] = (t < 256) ? bq[t] : bk[t - 256];
            else if (t < 1536) biasv[t] = bv[t - 512];
            else if (t < 2560) biasv[t] = b1[t - 1536];
            else               biasv[t] = b2[t - 2560];
        }
        return;
    }
    const float* src; u16* dst; int ld_src, kt, nt, nbase;
    if (bid < 128) {
        const int job = bid >> 6, t = bid & 63;
        src = job ? Wk : Wq; ld_src = 256;
        kt = t >> 2; nt = t & 3; nbase = job * 256 + nt * 64;
        dst = WqkT;
    } else {
        const int j = bid - 128, w = j >> 8, t = j & 255;
        src = (w == 0) ? Wv : (w == 1) ? W1 : W2; ld_src = 1024;
        kt = t >> 4; nt = t & 15; nbase = nt * 64;
        dst = (w == 0) ? WvT : (w == 1) ? W1T : W2T;
    }
    const int k0 = kt * 64;
    const int n0s = (ld_src == 256) ? (nbase & 255) : nbase;

    __shared__ float tile[64][65];
    // read 64 rows (k) x 64 cols (n), coalesced float4
    const int ri = tid >> 4, j4 = (tid & 15) * 4;
    #pragma unroll
    for (int rr = 0; rr < 4; rr++) {
        const int i = ri + rr * 16;
        const float4 v = *(const float4*)&src[(size_t)(k0 + i) * ld_src + n0s + j4];
        tile[j4 + 0][i] = v.x;
        tile[j4 + 1][i] = v.y;
        tile[j4 + 2][i] = v.z;
        tile[j4 + 3][i] = v.w;
    }
    __syncthreads();
    // write 64 n-rows x 64 k, coalesced u16
    const int n = tid >> 2, ks = (tid & 3) * 16;
    ushort4 o[4];
    #pragma unroll
    for (int c = 0; c < 4; c++) {
        o[c].x = f2bf(tile[n][ks + c * 4 + 0]);
        o[c].y = f2bf(tile[n][ks + c * 4 + 1]);
        o[c].z = f2bf(tile[n][ks + c * 4 + 2]);
        o[c].w = f2bf(tile[n][ks + c * 4 + 3]);
    }
    u16* drow = &dst[(size_t)(nbase + n) * 1024 + k0 + ks];
    #pragma unroll
    for (int c = 0; c < 4; c++) *(ushort4*)&drow[c * 4] = o[c];
}

__device__ __forceinline__ float wave_sum(float v) {
    #pragma unroll
    for (int off = 32; off > 0; off >>= 1) v += __shfl_xor(v, off, 64);
    return v;
}

// One block per (b,q) row. Fully vectorized: P has exact zeros for c in (r, kpad)
// (G3 masks the diagonal tile), so no per-element validity masking is needed.
__global__ __launch_bounds__(256)
void norm_kernel(const u16* __restrict__ attnb, float* __restrict__ attn,
                 float* __restrict__ linv)
{
    const int S = 2048;
    const int row = blockIdx.x;
    const int q = row & (S - 1);
    const int kpad = (q + 128) & ~127;   // ceil((q+1)/128)*128
    const u16* brow = attnb + (size_t)row * S;
    float* srow = attn + (size_t)row * S;
    __shared__ float red[4];
    const int tid = threadIdx.x, wv = tid >> 6, ln = tid & 63;
    const int k = tid * 8;

    float vals[8];
    float lsum = 0.f;
    if (k < kpad) {
        const ushort4 a = *(const ushort4*)&brow[k];
        const ushort4 b = *(const ushort4*)&brow[k + 4];
        vals[0] = bf2f(a.x); vals[1] = bf2f(a.y); vals[2] = bf2f(a.z); vals[3] = bf2f(a.w);
        vals[4] = bf2f(b.x); vals[5] = bf2f(b.y); vals[6] = bf2f(b.z); vals[7] = bf2f(b.w);
        #pragma unroll
        for (int c = 0; c < 8; c++) lsum += vals[c];
    }
    lsum = wave_sum(lsum);
    if (ln == 0) red[wv] = lsum;
    __syncthreads();
    const float rinv = 1.f / (red[0] + red[1] + red[2] + red[3]);

    float4 o0 = {0.f, 0.f, 0.f, 0.f}, o1 = {0.f, 0.f, 0.f, 0.f};
    if (k < kpad) {
        o0 = make_float4(vals[0] * rinv, vals[1] * rinv, vals[2] * rinv, vals[3] * rinv);
        o1 = make_float4(vals[4] * rinv, vals[5] * rinv, vals[6] * rinv, vals[7] * rinv);
    }
    *(float4*)&srow[k] = o0;
    *(float4*)&srow[k + 4] = o1;
    if (tid == 0) linv[row] = rinv;
}

extern "C" void kernel_launch(void* const* d_in, const int* in_sizes, int n_in,
                              void* d_out, int out_size, void* d_ws, size_t ws_size,
                              hipStream_t stream)
{
    const float* x  = (const float*)d_in[0];
    const float* Wq = (const float*)d_in[1];
    const float* bq = (const float*)d_in[2];
    const float* Wk = (const float*)d_in[3];
    const float* bk = (const float*)d_in[4];
    const float* Wv = (const float*)d_in[5];
    const float* bv = (const float*)d_in[6];
    const float* W1 = (const float*)d_in[7];
    const float* b1 = (const float*)d_in[8];
    const float* W2 = (const float*)d_in[9];
    const float* b2 = (const float*)d_in[10];

    const int B = 4, S = 2048, D = 1024, BS = B * S;

    char* ws = (char*)d_ws;
    u16*   xb    = (u16*)(ws + 0);            // 16 MB, aliased by h_b after G4
    u16*   WqkT  = (u16*)(ws + 16777216);     // 1 MB  (contiguous with WvT -> [1536][1024])
    u16*   WvT   = (u16*)(ws + 17825792);     // 2 MB
    u16*   W1T   = (u16*)(ws + 19922944);     // 2 MB
    u16*   W2T   = (u16*)(ws + 22020096);     // 2 MB
    float* biasv = (float*)(ws + 24117248);   // 16 KB: [bq|bk][bv][b1][b2]
    u16*   QK    = (u16*)(ws + 24133632);     // 8 MB: [8192][512] = [Q|K]
    u16*   Vt    = (u16*)(ws + 32522240);     // 16 MB: [4][1024][2048]
    u16*   attnb = (u16*)(ws + 49299456);     // 32 MB raw exp-P, aliased by ff1 after G4
    float* linv  = (float*)(ws + 83886080);   // 32 KB
    u16*   hb    = xb;
    u16*   ff1   = attnb;

    float* out0 = (float*)d_out;
    float* attn = out0 + (size_t)BS * D;

    const dim3 blk(256);

    prep_x<<<dim3(1024), blk, 0, stream>>>(x, xb);
    prep_w<<<dim3(897), blk, 0, stream>>>(Wq, bq, Wk, bk, Wv, bv, b1, b2, W1, W2,
                                          WqkT, WvT, W1T, W2T, biasv);

    // G12 merged: [Q|K|V] = x @ [Wq|Wk|Wv] + bias   (M=8192, N=1536, K=1024, 384 blocks)
    gemm_bt2<6><<<dim3(12, 32), dim3(512), 0, stream>>>(
        xb, 1024, WqkT, 1024, 512, biasv, Vt, QK);

    // G3: P = exp(Q @ K^T / 16), causal-masked, bf16, triangular grid (544 blocks)
    gemm_bt<2><<<dim3(136, 4, 1), blk, 0, stream>>>(
        QK, 512, (long long)S * 512, QK + 256, 512, (long long)S * 512,
        256, S, (long long)S * S, nullptr, 0.0625f, nullptr, 0, attnb, 3);

    // normalize: attn_fp32 = P / l (d_out), linv = 1/l
    norm_kernel<<<dim3(BS), blk, 0, stream>>>(attnb, attn, linv);

    // G4: h = bf16(x) + (P @ V) * linv  (512 blocks, K clipped at diagonal, by-pairing)
    gemm_bt<3><<<dim3(8, 16, 4), blk, 0, stream>>>(
        attnb, S, (long long)S * S, Vt, S, (long long)D * S,
        S, D, (long long)S * D, linv, 1.f, xb, (long long)S * D, hb, 2);

    // G5: ff1 = relu(h @ W1 + b1)  (M=8192, N=1024, K=1024, 256 blocks)
    gemm_bt2<4><<<dim3(8, 32), dim3(512), 0, stream>>>(
        hb, 1024, W1T, 1024, 1024, biasv + 1536, nullptr, ff1);

    // G6: out0 = h + ff1 @ W2 + b2  (M=8192, N=1024, K=1024, 256 blocks)
    gemm_bt2<5><<<dim3(8, 32), dim3(512), 0, stream>>>(
        ff1, 1024, W2T, 1024, 1024, biasv + 2560, hb, out0);
}

// Round 7
// 292.082 us; speedup vs baseline: 1.1317x; 1.0394x over previous
//
#include <hip/hip_runtime.h>
#include <hip/hip_bf16.h>

#define BM 128
#define BN 128

typedef __bf16 bf16x8 __attribute__((ext_vector_type(8)));
typedef float f32x4 __attribute__((ext_vector_type(4)));
typedef unsigned short u16;

__device__ __forceinline__ u16 f2bf(float f) {
    __bf16 b = (__bf16)f;
    return __builtin_bit_cast(u16, b);
}
__device__ __forceinline__ float bf2f(u16 u) {
    __bf16 b = __builtin_bit_cast(__bf16, u);
    return (float)b;
}

__device__ __forceinline__ void gload_lds16(const void* g, void* l) {
    __builtin_amdgcn_global_load_lds(
        (const __attribute__((address_space(1))) void*)g,
        (__attribute__((address_space(3))) void*)l,
        16, 0, 0);
}

// Inline-asm LDS read: invisible to the memory legalizer, so it cannot insert
// conservative vmcnt drains against outstanding global_load_lds DMA. Completion
// is enforced manually via counted lgkmcnt + sched_barrier(0) (rule #18).
__device__ __forceinline__ bf16x8 lds_read_b128(const u16* p) {
    bf16x8 r;
    const __attribute__((address_space(3))) u16* lp =
        (const __attribute__((address_space(3))) u16*)p;
    asm volatile("ds_read_b128 %0, %1" : "=v"(r) : "v"(lp));
    return r;
}

// ---------------------------------------------------------------------------
// Legacy 128x128 kernel — retained ONLY for G3 (MODE 2, triangular grid).
// ---------------------------------------------------------------------------
template <int MODE>
__global__ __launch_bounds__(256)
void gemm_bt(const u16* __restrict__ A, int lda, long long a_bs,
             const u16* __restrict__ Bt, int ldb, long long b_bs,
             int Kdim, int ldc, long long c_bs,
             const float* __restrict__ bias, float scale,
             const void* __restrict__ resid, long long r_bs,
             void* __restrict__ out, int causal)
{
    int bx = blockIdx.x, by = blockIdx.y, bz = blockIdx.z;
    if (causal == 3) {
        const int t = blockIdx.x;
        int byy = (int)((sqrtf(8.f * (float)t + 1.f) - 1.f) * 0.5f);
        while ((byy + 1) * (byy + 2) / 2 <= t) byy++;
        while (byy * (byy + 1) / 2 > t) byy--;
        by = byy; bx = t - byy * (byy + 1) / 2; bz = blockIdx.y;
    }
    const int kend = Kdim;

    A  += (long long)bz * a_bs;
    Bt += (long long)bz * b_bs;

    const int m0 = by * BM, n0 = bx * BN;
    const int tid = threadIdx.x;
    const int wave = tid >> 6, lane = tid & 63;
    const int wy = wave >> 1, wx = wave & 1;
    const int lr = lane >> 2, lc8 = (lane & 3) * 8;
    const int lane15 = lane & 15, kq = lane >> 4;

    __shared__ __align__(16) u16 As[2][BM * 32];
    __shared__ __align__(16) u16 Bs[2][BN * 32];

    f32x4 acc[4][4] = {};

    for (int k0 = 0; k0 < kend; k0 += 64) {
        __syncthreads();
        #pragma unroll
        for (int h = 0; h < 2; h++) {
            const int kh = k0 + h * 32 + lc8;
            #pragma unroll
            for (int it = 0; it < 2; it++) {
                const int row = wave * 16 + it * 64 + lr;
                gload_lds16(A  + (size_t)(m0 + row) * lda + kh,
                            &As[h][(wave * 16 + it * 64) * 32]);
                gload_lds16(Bt + (size_t)(n0 + row) * ldb + kh,
                            &Bs[h][(wave * 16 + it * 64) * 32]);
            }
        }
        __syncthreads();

        #pragma unroll
        for (int h = 0; h < 2; h++) {
            bf16x8 av[4], bv[4];
            #pragma unroll
            for (int i = 0; i < 4; i++)
                av[i] = *(const bf16x8*)&As[h][(wy * 64 + i * 16 + lane15) * 32 + kq * 8];
            #pragma unroll
            for (int j = 0; j < 4; j++)
                bv[j] = *(const bf16x8*)&Bs[h][(wx * 64 + j * 16 + lane15) * 32 + kq * 8];
            #pragma unroll
            for (int i = 0; i < 4; i++)
                #pragma unroll
                for (int j = 0; j < 4; j++)
                    acc[i][j] = __builtin_amdgcn_mfma_f32_16x16x32_bf16(av[i], bv[j], acc[i][j], 0, 0, 0);
        }
    }

    // Epilogue. C/D layout (m89-verified): col = lane&15, row = (lane>>4)*4 + reg.
    #pragma unroll
    for (int i = 0; i < 4; i++) {
        const int rl = m0 + wy * 64 + i * 16 + kq * 4;
        #pragma unroll
        for (int j = 0; j < 4; j++) {
            const int c = n0 + wx * 64 + j * 16 + lane15;
            #pragma unroll
            for (int rg = 0; rg < 4; rg++) {
                const int r = rl + rg;
                const size_t idx = (size_t)bz * c_bs + (size_t)r * ldc + c;
                const float v = acc[i][j][rg];
                if (MODE == 2) {
                    float p = __expf(v * scale);
                    if (c > r) p = 0.f;          // causal mask inside diagonal tile
                    ((u16*)out)[idx] = f2bf(p);
                }
            }
        }
    }
}

// ---------------------------------------------------------------------------
// gemm_bt3: 128x128 tile, 256 threads (4 waves, 2x2), BK=64, ring-2 double
// buffer (64 KiB LDS -> 2 blocks/CU). Synthesis of what worked:
//  - counted vmcnt(8) (8 gload_lds per tile per wave; 1-tile lead; vmcnt(0)
//    only at the final tile) — no legalizer drains (asm ds_read, rule #18)
//  - bank swizzle: pre-swizzled global source + swizzled asm ds_read (0 confl)
//  - 2 blocks/CU: cross-block TLP hides the vmcnt/barrier windows (m114),
//    which round-6's 1-block/CU structure lacked.
// Per tile t: { [t>0] barrier (reads of buf[(t+1)&1] done) ->
//   stage(t+1 -> buf[(t+1)&1]) -> vmcnt(8) -> barrier (publish tile t) ->
//   16 asm ds_read (h0,h1) -> lgkmcnt(8)+schedbar -> 16 MFMA h0 ->
//   lgkmcnt(0)+schedbar -> 16 MFMA h1 }
// Ledger: at stage time outstanding = t's 8; after stage 16; vmcnt(8) retires
// exactly tile t's loads (issued one tile earlier). Buffer overwrite safe:
// barrier1 proves all waves' reads of that buffer drained (their lgkmcnt(0)
// precedes their MFMA h1 which precedes barrier1).
//
// causal: 0 = none (+T1 XCD remap; requires nwg%8==0), 2 = K-clip at
// (by+1)*128 + by-pairing via bz>=2 flip (G4; no T1).
// MODE 3: bf16 out = resid + acc*linv[row]; 4: relu(acc+bias);
// MODE 5: fp32 out = acc+bias+resid; 6: QKV merged (n0>=512 -> Vt transposed)
// ---------------------------------------------------------------------------
template <int MODE>
__global__ __launch_bounds__(256, 2)
void gemm_bt3(const u16* __restrict__ A, int lda, long long a_bs,
              const u16* __restrict__ Bt, int ldb, long long b_bs,
              int Kdim, int ldc, long long c_bs,
              const float* __restrict__ bias,
              const void* __restrict__ resid, long long r_bs,
              void* __restrict__ out, int causal)
{
    int bx = blockIdx.x, by = blockIdx.y;
    const int bz = blockIdx.z;
    if (causal == 0) {
        const int gx = gridDim.x;
        const int nwg = gx * (int)gridDim.y;
        int lin = by * gx + bx;
        lin = (lin & 7) * (nwg >> 3) + (lin >> 3);   // T1: contiguous chunk per XCD
        by = lin / gx; bx = lin % gx;
    } else if (causal == 2 && bz >= 2) {
        by = (int)gridDim.y - 1 - by;                // pair long/short K rows
    }
    const int kend = (causal == 2) ? min(Kdim, (by + 1) * 128) : Kdim;
    const int NT = kend >> 6;

    A  += (long long)bz * a_bs;
    Bt += (long long)bz * b_bs;

    const int m0 = by * 128, n0 = bx * 128;
    const int tid = threadIdx.x;
    const int wave = tid >> 6, lane = tid & 63;
    const int wy = wave >> 1, wx = wave & 1;          // 2x2 wave grid
    const int lane15 = lane & 15, kq = lane >> 4;
    const int lr = lane >> 2;
    const int swzc8 = ((lane & 3) ^ ((lane >> 3) & 3)) * 8;               // staging source k-slot
    const int lslot = lane15 * 32 + ((kq ^ ((lane15 >> 1) & 3)) * 8);     // swizzled read offset

    __shared__ __align__(16) u16 As[2][2][128 * 32];   // [buf][h] 32 KiB
    __shared__ __align__(16) u16 Bs[2][2][128 * 32];   // 32 KiB; total 64 KiB

    f32x4 acc[4][4] = {};

    // 8 VMEM instr per wave per tile: 4 A + 4 B.
    auto stage = [&](int buf, int tt) {
        #pragma unroll
        for (int h = 0; h < 2; h++) {
            const int kh = (tt << 6) + h * 32 + swzc8;
            #pragma unroll
            for (int it = 0; it < 2; it++) {
                const int row = wave * 16 + it * 64 + lr;
                gload_lds16(A + (size_t)(m0 + row) * lda + kh,
                            &As[buf][h][(wave * 16 + it * 64) * 32]);
                gload_lds16(Bt + (size_t)(n0 + row) * ldb + kh,
                            &Bs[buf][h][(wave * 16 + it * 64) * 32]);
            }
        }
    };

    stage(0, 0);

    for (int t = 0; t < NT; t++) {
        const int cur = t & 1;
        if (t) __builtin_amdgcn_s_barrier();          // reads of buf[cur^1] done
        if (t + 1 < NT) {
            stage(cur ^ 1, t + 1);
            asm volatile("s_waitcnt vmcnt(8)" ::: "memory");   // tile t landed
        } else {
            asm volatile("s_waitcnt vmcnt(0)" ::: "memory");
        }
        __builtin_amdgcn_s_barrier();                 // publish tile t

        bf16x8 av0[4], bv0[4], av1[4], bv1[4];
        #pragma unroll
        for (int i = 0; i < 4; i++)
            av0[i] = lds_read_b128(&As[cur][0][(wy * 64 + i * 16) * 32 + lslot]);
        #pragma unroll
        for (int j = 0; j < 4; j++)
            bv0[j] = lds_read_b128(&Bs[cur][0][(wx * 64 + j * 16) * 32 + lslot]);
        #pragma unroll
        for (int i = 0; i < 4; i++)
            av1[i] = lds_read_b128(&As[cur][1][(wy * 64 + i * 16) * 32 + lslot]);
        #pragma unroll
        for (int j = 0; j < 4; j++)
            bv1[j] = lds_read_b128(&Bs[cur][1][(wx * 64 + j * 16) * 32 + lslot]);

        asm volatile("s_waitcnt lgkmcnt(8)" ::: "memory");
        __builtin_amdgcn_sched_barrier(0);
        __builtin_amdgcn_s_setprio(1);
        #pragma unroll
        for (int i = 0; i < 4; i++)
            #pragma unroll
            for (int j = 0; j < 4; j++)
                acc[i][j] = __builtin_amdgcn_mfma_f32_16x16x32_bf16(av0[i], bv0[j], acc[i][j], 0, 0, 0);
        __builtin_amdgcn_s_setprio(0);

        asm volatile("s_waitcnt lgkmcnt(0)" ::: "memory");
        __builtin_amdgcn_sched_barrier(0);
        __builtin_amdgcn_s_setprio(1);
        #pragma unroll
        for (int i = 0; i < 4; i++)
            #pragma unroll
            for (int j = 0; j < 4; j++)
                acc[i][j] = __builtin_amdgcn_mfma_f32_16x16x32_bf16(av1[i], bv1[j], acc[i][j], 0, 0, 0);
        __builtin_amdgcn_s_setprio(0);
    }

    // Epilogue. C/D layout: col = lane&15, row = (lane>>4)*4 + reg.
    if (MODE == 6 && n0 >= 512) {
        u16* o = (u16*)resid;  // Vt[b][c-512][s], second output pointer
        #pragma unroll
        for (int i = 0; i < 4; i++) {
            const int r = m0 + wy * 64 + i * 16 + kq * 4;
            const size_t base = (size_t)(r >> 11) * 1024 * 2048 + (r & 2047);
            #pragma unroll
            for (int j = 0; j < 4; j++) {
                const int c = n0 + wx * 64 + j * 16 + lane15;
                const float bj = bias[c];
                ushort4 pk;
                pk.x = f2bf(acc[i][j][0] + bj);
                pk.y = f2bf(acc[i][j][1] + bj);
                pk.z = f2bf(acc[i][j][2] + bj);
                pk.w = f2bf(acc[i][j][3] + bj);
                *(ushort4*)&o[base + (size_t)(c - 512) * 2048] = pk;
            }
        }
    } else {
        #pragma unroll
        for (int i = 0; i < 4; i++) {
            const int rl = m0 + wy * 64 + i * 16 + kq * 4;
            #pragma unroll
            for (int j = 0; j < 4; j++) {
                const int c = n0 + wx * 64 + j * 16 + lane15;
                float bj = 0.f;
                if (MODE == 4 || MODE == 5 || MODE == 6) bj = bias[c];
                #pragma unroll
                for (int rg = 0; rg < 4; rg++) {
                    const int r = rl + rg;
                    const size_t idx = (size_t)bz * c_bs + (size_t)r * ldc + c;
                    const float v = acc[i][j][rg];
                    if (MODE == 3) {
                        const u16* xr = (const u16*)resid;
                        const float linv = bias[(size_t)bz * 2048 + r];
                        const float h = bf2f(xr[(size_t)bz * r_bs + (size_t)r * ldc + c]) + v * linv;
                        ((u16*)out)[idx] = f2bf(h);
                    } else if (MODE == 4) {
                        ((u16*)out)[idx] = f2bf(fmaxf(v + bj, 0.f));
                    } else if (MODE == 5) {
                        const u16* hb = (const u16*)resid;
                        ((float*)out)[idx] = v + bj + bf2f(hb[(size_t)r * ldc + c]);
                    } else if (MODE == 6) {
                        ((u16*)out)[idx] = f2bf(v + bj);
                    }
                }
            }
        }
    }
}

// x fp32 -> bf16, vectorized (float4 in, ushort4 out).
__global__ __launch_bounds__(256)
void prep_x(const float* __restrict__ x, u16* __restrict__ xb)
{
    const int N4 = 8388608 / 4;
    for (int i = blockIdx.x * blockDim.x + threadIdx.x; i < N4; i += gridDim.x * blockDim.x) {
        const float4 v = ((const float4*)x)[i];
        ushort4 o;
        o.x = f2bf(v.x); o.y = f2bf(v.y); o.z = f2bf(v.z); o.w = f2bf(v.w);
        ((ushort4*)xb)[i] = o;
    }
}

// Coalesced LDS-tiled transpose+convert of all weights, plus bias concat.
__global__ __launch_bounds__(256)
void prep_w(const float* __restrict__ Wq, const float* __restrict__ bq,
            const float* __restrict__ Wk, const float* __restrict__ bk,
            const float* __restrict__ Wv, const float* __restrict__ bv,
            const float* __restrict__ b1, const float* __restrict__ b2,
            const float* __restrict__ W1, const float* __restrict__ W2,
            u16* __restrict__ WqkT, u16* __restrict__ WvT,
            u16* __restrict__ W1T, u16* __restrict__ W2T, float* __restrict__ biasv)
{
    const int bid = blockIdx.x, tid = threadIdx.x;
    if (bid == 896) {
        for (int t = tid; t < 3584; t += 256) {
            if (t < 512)       biasv[t] = (t < 256) ? bq[t] : bk[t - 256];
            else if (t < 1536) biasv[t] = bv[t - 512];
            else if (t < 2560) biasv[t] = b1[t - 1536];
            else               biasv[t] = b2[t - 2560];
        }
        return;
    }
    const float* src; u16* dst; int ld_src, kt, nt, nbase;
    if (bid < 128) {
        const int job = bid >> 6, t = bid & 63;
        src = job ? Wk : Wq; ld_src = 256;
        kt = t >> 2; nt = t & 3; nbase = job * 256 + nt * 64;
        dst = WqkT;
    } else {
        const int j = bid - 128, w = j >> 8, t = j & 255;
        src = (w == 0) ? Wv : (w == 1) ? W1 : W2; ld_src = 1024;
        kt = t >> 4; nt = t & 15; nbase = nt * 64;
        dst = (w == 0) ? WvT : (w == 1) ? W1T : W2T;
    }
    const int k0 = kt * 64;
    const int n0s = (ld_src == 256) ? (nbase & 255) : nbase;

    __shared__ float tile[64][65];
    const int ri = tid >> 4, j4 = (tid & 15) * 4;
    #pragma unroll
    for (int rr = 0; rr < 4; rr++) {
        const int i = ri + rr * 16;
        const float4 v = *(const float4*)&src[(size_t)(k0 + i) * ld_src + n0s + j4];
        tile[j4 + 0][i] = v.x;
        tile[j4 + 1][i] = v.y;
        tile[j4 + 2][i] = v.z;
        tile[j4 + 3][i] = v.w;
    }
    __syncthreads();
    const int n = tid >> 2, ks = (tid & 3) * 16;
    ushort4 o[4];
    #pragma unroll
    for (int c = 0; c < 4; c++) {
        o[c].x = f2bf(tile[n][ks + c * 4 + 0]);
        o[c].y = f2bf(tile[n][ks + c * 4 + 1]);
        o[c].z = f2bf(tile[n][ks + c * 4 + 2]);
        o[c].w = f2bf(tile[n][ks + c * 4 + 3]);
    }
    u16* drow = &dst[(size_t)(nbase + n) * 1024 + k0 + ks];
    #pragma unroll
    for (int c = 0; c < 4; c++) *(ushort4*)&drow[c * 4] = o[c];
}

__device__ __forceinline__ float wave_sum(float v) {
    #pragma unroll
    for (int off = 32; off > 0; off >>= 1) v += __shfl_xor(v, off, 64);
    return v;
}

// One block per (b,q) row.
__global__ __launch_bounds__(256)
void norm_kernel(const u16* __restrict__ attnb, float* __restrict__ attn,
                 float* __restrict__ linv)
{
    const int S = 2048;
    const int row = blockIdx.x;
    const int q = row & (S - 1);
    const int kpad = (q + 128) & ~127;   // ceil((q+1)/128)*128
    const u16* brow = attnb + (size_t)row * S;
    float* srow = attn + (size_t)row * S;
    __shared__ float red[4];
    const int tid = threadIdx.x, wv = tid >> 6, ln = tid & 63;
    const int k = tid * 8;

    float vals[8];
    float lsum = 0.f;
    if (k < kpad) {
        const ushort4 a = *(const ushort4*)&brow[k];
        const ushort4 b = *(const ushort4*)&brow[k + 4];
        vals[0] = bf2f(a.x); vals[1] = bf2f(a.y); vals[2] = bf2f(a.z); vals[3] = bf2f(a.w);
        vals[4] = bf2f(b.x); vals[5] = bf2f(b.y); vals[6] = bf2f(b.z); vals[7] = bf2f(b.w);
        #pragma unroll
        for (int c = 0; c < 8; c++) lsum += vals[c];
    }
    lsum = wave_sum(lsum);
    if (ln == 0) red[wv] = lsum;
    __syncthreads();
    const float rinv = 1.f / (red[0] + red[1] + red[2] + red[3]);

    float4 o0 = {0.f, 0.f, 0.f, 0.f}, o1 = {0.f, 0.f, 0.f, 0.f};
    if (k < kpad) {
        o0 = make_float4(vals[0] * rinv, vals[1] * rinv, vals[2] * rinv, vals[3] * rinv);
        o1 = make_float4(vals[4] * rinv, vals[5] * rinv, vals[6] * rinv, vals[7] * rinv);
    }
    *(float4*)&srow[k] = o0;
    *(float4*)&srow[k + 4] = o1;
    if (tid == 0) linv[row] = rinv;
}

extern "C" void kernel_launch(void* const* d_in, const int* in_sizes, int n_in,
                              void* d_out, int out_size, void* d_ws, size_t ws_size,
                              hipStream_t stream)
{
    const float* x  = (const float*)d_in[0];
    const float* Wq = (const float*)d_in[1];
    const float* bq = (const float*)d_in[2];
    const float* Wk = (const float*)d_in[3];
    const float* bk = (const float*)d_in[4];
    const float* Wv = (const float*)d_in[5];
    const float* bv = (const float*)d_in[6];
    const float* W1 = (const float*)d_in[7];
    const float* b1 = (const float*)d_in[8];
    const float* W2 = (const float*)d_in[9];
    const float* b2 = (const float*)d_in[10];

    const int B = 4, S = 2048, D = 1024, BS = B * S;

    char* ws = (char*)d_ws;
    u16*   xb    = (u16*)(ws + 0);            // 16 MB, aliased by h_b after G4
    u16*   WqkT  = (u16*)(ws + 16777216);     // 1 MB
    u16*   WvT   = (u16*)(ws + 17825792);     // 2 MB
    u16*   W1T   = (u16*)(ws + 19922944);     // 2 MB
    u16*   W2T   = (u16*)(ws + 22020096);     // 2 MB
    float* biasv = (float*)(ws + 24117248);   // 16 KB
    u16*   QK    = (u16*)(ws + 24133632);     // 8 MB: [8192][512] = [Q|K]
    u16*   Vt    = (u16*)(ws + 32522240);     // 16 MB: [4][1024][2048]
    u16*   attnb = (u16*)(ws + 49299456);     // 32 MB raw exp-P, aliased by ff1
    float* linv  = (float*)(ws + 83886080);   // 32 KB
    u16*   hb    = xb;
    u16*   ff1   = attnb;

    float* out0 = (float*)d_out;
    float* attn = out0 + (size_t)BS * D;

    const dim3 blk(256);

    prep_x<<<dim3(1024), blk, 0, stream>>>(x, xb);
    prep_w<<<dim3(897), blk, 0, stream>>>(Wq, bq, Wk, bk, Wv, bv, b1, b2, W1, W2,
                                          WqkT, WvT, W1T, W2T, biasv);

    // G12 merged: [Q|K|V] = x @ [Wq|Wk|Wv] + bias   (M=8192, N=1536, K=1024, 768 blocks)
    gemm_bt3<6><<<dim3(12, 64, 1), blk, 0, stream>>>(
        xb, 1024, 0, WqkT, 1024, 0, 1024, 512, 0,
        biasv, Vt, 0, QK, 0);

    // G3: P = exp(Q @ K^T / 16), causal-masked, bf16, triangular grid (544 blocks)
    gemm_bt<2><<<dim3(136, 4, 1), blk, 0, stream>>>(
        QK, 512, (long long)S * 512, QK + 256, 512, (long long)S * 512,
        256, S, (long long)S * S, nullptr, 0.0625f, nullptr, 0, attnb, 3);

    // normalize: attn_fp32 = P / l (d_out), linv = 1/l
    norm_kernel<<<dim3(BS), blk, 0, stream>>>(attnb, attn, linv);

    // G4: h = bf16(x) + (P @ V) * linv  (512 blocks, K clipped at diagonal, by-pairing)
    gemm_bt3<3><<<dim3(8, 16, 4), blk, 0, stream>>>(
        attnb, S, (long long)S * S, Vt, S, (long long)D * S,
        S, D, (long long)S * D, linv, xb, (long long)S * D, hb, 2);

    // G5: ff1 = relu(h @ W1 + b1)  (M=8192, N=1024, K=1024, 512 blocks)
    gemm_bt3<4><<<dim3(8, 64, 1), blk, 0, stream>>>(
        hb, 1024, 0, W1T, 1024, 0, 1024, 1024, 0,
        biasv + 1536, nullptr, 0, ff1, 0);

    // G6: out0 = h + ff1 @ W2 + b2  (M=8192, N=1024, K=1024, 512 blocks)
    gemm_bt3<5><<<dim3(8, 64, 1), blk, 0, stream>>>(
        ff1, 1024, 0, W2T, 1024, 0, 1024, 1024, 0,
        biasv + 2560, hb, 0, out0, 0);
}